// Round 1
// baseline (231.032 us; speedup 1.0000x reference)
//
#include <hip/hip_runtime.h>

#define BB 32
#define NP 2048
#define NG 2048
#define LDIM 256
#define EPSF 1e-6f
#define BIGF 1e18f

// acc layout (floats):
//  0: sum min_dist_pred (masked min, over B*Np)
//  1: sum |pred_E - matched_E|
//  2: sum entropy terms  p*log(p+eps)+(1-p)*log(1-p+eps)
//  3: sum min_dist_target * mask
//  4: total mask sum
//  5: kld term sum  (1 + logvar - mu^2 - exp(logvar))
//  8..39  : per-b sum pred_hit
//  40..71 : per-b sum pred_E*pred_hit
//  72..103: per-b mask sum
#define ACC_FLOATS 104

__device__ __forceinline__ void wave_acc(float v, float* dst) {
  v += __shfl_down(v, 32);
  v += __shfl_down(v, 16);
  v += __shfl_down(v, 8);
  v += __shfl_down(v, 4);
  v += __shfl_down(v, 2);
  v += __shfl_down(v, 1);
  if ((threadIdx.x & 63) == 0) atomicAdd(dst, v);
}

// Pred side: masked min over targets + argmin -> chamfer_pred, local_E.
// Also per-thread elementwise pieces: entropy, hit count, E*hit.
__global__ __launch_bounds__(256) void k_pred(const float* __restrict__ preds,
                                              const float* __restrict__ target,
                                              const float* __restrict__ mask,
                                              float* __restrict__ acc) {
  __shared__ float4 t4[NG];
  const int b = blockIdx.x >> 3;
  const int chunk = blockIdx.x & 7;
  const int tid = threadIdx.x;
  const float* tb = target + b * 4 * NG;
  const float* mb = mask + b * NG;
  for (int m = tid; m < NG; m += 256) {
    float tx = tb[m], ty = tb[NG + m], tz = tb[2 * NG + m];
    float tn = tx * tx + ty * ty + tz * tz;
    float w = tn + (mb[m] == 0.0f ? BIGF : 0.0f);  // fold BIG mask into the constant term
    t4[m] = make_float4(-2.0f * tx, -2.0f * ty, -2.0f * tz, w);
  }
  __syncthreads();

  const int n = chunk * 256 + tid;
  const float* pb = preds + b * 5 * NP;
  const float px = pb[n], py = pb[NP + n], pz = pb[2 * NP + n];
  const float pE = pb[3 * NP + n], ph = pb[4 * NP + n];
  const float pn2 = px * px + py * py + pz * pz;

  // two independent min/argmin chains (even/odd m) for ILP; strict < keeps first index
  float best0 = 3.4e38f, best1 = 3.4e38f;
  int idx0 = 0, idx1 = 1;
#pragma unroll 4
  for (int m = 0; m < NG; m += 2) {
    float4 t = t4[m];
    float4 u = t4[m + 1];
    float d0 = fmaf(px, t.x, fmaf(py, t.y, fmaf(pz, t.z, pn2 + t.w)));
    float d1 = fmaf(px, u.x, fmaf(py, u.y, fmaf(pz, u.z, pn2 + u.w)));
    d0 = fmaxf(d0, 0.0f);
    d1 = fmaxf(d1, 0.0f);
    if (d0 < best0) { best0 = d0; idx0 = m; }
    if (d1 < best1) { best1 = d1; idx1 = m + 1; }
  }
  if (best1 < best0 || (best1 == best0 && idx1 < idx0)) { best0 = best1; idx0 = idx1; }

  float mE = tb[3 * NG + idx0];  // matched target_E (L2-resident gather)
  float localE = fabsf(pE - mE);
  float ent = ph * logf(ph + EPSF) + (1.0f - ph) * logf(1.0f - ph + EPSF);

  wave_acc(best0, &acc[0]);
  wave_acc(localE, &acc[1]);
  wave_acc(ent, &acc[2]);
  wave_acc(ph, &acc[8 + b]);
  wave_acc(pE * ph, &acc[40 + b]);
}

// Target side: unmasked min over preds, weighted by mask. Also per-b mask sums.
__global__ __launch_bounds__(256) void k_tgt(const float* __restrict__ preds,
                                             const float* __restrict__ target,
                                             const float* __restrict__ mask,
                                             float* __restrict__ acc) {
  __shared__ float4 p4[NP];
  const int b = blockIdx.x >> 3;
  const int chunk = blockIdx.x & 7;
  const int tid = threadIdx.x;
  const float* pb = preds + b * 5 * NP;
  for (int n = tid; n < NP; n += 256) {
    float px = pb[n], py = pb[NP + n], pz = pb[2 * NP + n];
    float pn2 = px * px + py * py + pz * pz;
    p4[n] = make_float4(-2.0f * px, -2.0f * py, -2.0f * pz, pn2);
  }
  __syncthreads();

  const int m = chunk * 256 + tid;
  const float* tb = target + b * 4 * NG;
  const float tx = tb[m], ty = tb[NG + m], tz = tb[2 * NG + m];
  const float tn = tx * tx + ty * ty + tz * tz;
  const float msk = mask[b * NG + m];

  float best0 = 3.4e38f, best1 = 3.4e38f;
#pragma unroll 4
  for (int n = 0; n < NP; n += 2) {
    float4 p = p4[n];
    float4 q = p4[n + 1];
    float d0 = fmaxf(fmaf(tx, p.x, fmaf(ty, p.y, fmaf(tz, p.z, tn + p.w))), 0.0f);
    float d1 = fmaxf(fmaf(tx, q.x, fmaf(ty, q.y, fmaf(tz, q.z, tn + q.w))), 0.0f);
    best0 = fminf(best0, d0);
    best1 = fminf(best1, d1);
  }
  float best = fminf(best0, best1);

  wave_acc(best * msk, &acc[3]);
  wave_acc(msk, &acc[4]);
  wave_acc(msk, &acc[72 + b]);
}

__global__ __launch_bounds__(256) void k_kld(const float* __restrict__ mu,
                                             const float* __restrict__ logvar,
                                             float* __restrict__ acc) {
  int i = blockIdx.x * 256 + threadIdx.x;  // B*L = 8192 exactly
  float m = mu[i], lv = logvar[i];
  float term = 1.0f + lv - m * m - expf(lv);
  wave_acc(term, &acc[5]);
}

__global__ __launch_bounds__(64) void k_final(const float* __restrict__ acc,
                                              const float* __restrict__ e_init,
                                              const float* __restrict__ kl_weight,
                                              float* __restrict__ out) {
  int t = threadIdx.x;
  float hitsq = 0.0f, esq = 0.0f;
  if (t < BB) {
    float nhp = acc[8 + t];
    float nht = acc[72 + t];
    float dh = nhp - nht;
    hitsq = dh * dh;
    float de = acc[40 + t] - e_init[t];
    esq = de * de;
  }
  for (int o = 32; o > 0; o >>= 1) {
    hitsq += __shfl_down(hitsq, o);
    esq += __shfl_down(esq, o);
  }
  if (t == 0) {
    const float invBN = 1.0f / (float)(BB * NP);
    float chamfer_pred = acc[0] * invBN;
    float localE = acc[1] * invBN;
    float ent = -acc[2] * invBN;
    float chamfer_tgt = acc[3] / acc[4];
    float kld = -0.5f * acc[5] / (float)BB;
    float hit = hitsq / (float)BB;
    float ge = esq / (float)BB;

    float loss_chamf = (chamfer_tgt + chamfer_pred) * 0.001f;  // LAMBDA_CHAMFER
    float losskld = kl_weight[0] * kld;
    float loss_ge = 10.0f * ge;     // LAMBDA_E_SUM
    float loss_hit = 20.0f * hit;   // LAMBDA_HIT
    float loss_ent = 0.1f * ent;    // LAMBDA_HIT_ENTROPY

    float total = loss_chamf + localE + losskld + loss_ge + loss_hit + loss_ent;
    out[0] = total;
    out[1] = loss_chamf;
    out[2] = localE;
    out[3] = loss_ge;
    out[4] = loss_hit;
    out[5] = losskld;
  }
}

extern "C" void kernel_launch(void* const* d_in, const int* in_sizes, int n_in,
                              void* d_out, int out_size, void* d_ws, size_t ws_size,
                              hipStream_t stream) {
  const float* preds = (const float*)d_in[0];
  const float* target = (const float*)d_in[1];
  const float* mask = (const float*)d_in[2];
  const float* mu = (const float*)d_in[3];
  const float* logvar = (const float*)d_in[4];
  const float* e_init = (const float*)d_in[5];
  const float* kl_weight = (const float*)d_in[6];
  float* acc = (float*)d_ws;
  float* out = (float*)d_out;

  hipMemsetAsync(acc, 0, ACC_FLOATS * sizeof(float), stream);
  k_pred<<<BB * 8, 256, 0, stream>>>(preds, target, mask, acc);
  k_tgt<<<BB * 8, 256, 0, stream>>>(preds, target, mask, acc);
  k_kld<<<(BB * LDIM) / 256, 256, 0, stream>>>(mu, logvar, acc);
  k_final<<<1, 64, 0, stream>>>(acc, e_init, kl_weight, out);
}

// Round 2
// 183.668 us; speedup vs baseline: 1.2579x; 1.2579x over previous
//
#include <hip/hip_runtime.h>

#define BB 32
#define NP 2048
#define NG 2048
#define LDIM 256
#define EPSF 1e-6f
#define BIGF 1e18f
#define FLTMAX 3.4e38f

// ws layout:
//  [0, 416)           : float acc[104] (zeroed)
//  [4096, 4096+512K)  : u64 pred packed min  (dist_bits<<32 | idx), init 0xFF
//  [4096+512K, +256K) : u32 tgt min dist bits, init 0xFF
#define ACC_FLOATS 104
#define PRED_OFF 4096
#define TGT_OFF (4096 + NP * BB * 8)

__device__ __forceinline__ void wave_acc(float v, float* dst) {
  v += __shfl_down(v, 32);
  v += __shfl_down(v, 16);
  v += __shfl_down(v, 8);
  v += __shfl_down(v, 4);
  v += __shfl_down(v, 2);
  v += __shfl_down(v, 1);
  if ((threadIdx.x & 63) == 0) atomicAdd(dst, v);
}

// grid: 32 b * 4 nchunk * 8 mpart = 1024 blocks. Each block: 512 n-points
// (2 per thread), 256 m-points staged in LDS. Partial min/argmin combined
// across mparts via packed-u64 atomicMin (dist>=0 -> bits monotonic; tie ->
// smallest idx, matching jnp.argmin first-index).
__global__ __launch_bounds__(256) void k_pred(const float* __restrict__ preds,
                                              const float* __restrict__ target,
                                              const float* __restrict__ mask,
                                              unsigned long long* __restrict__ pmin) {
  __shared__ float4 t4[256];
  const int bx = blockIdx.x;
  const int b = bx >> 5;
  const int nch = (bx >> 3) & 3;
  const int mp = bx & 7;
  const int tid = threadIdx.x;
  const float* tb = target + b * 4 * NG;
  const int mbase = mp * 256;
  {
    int m = mbase + tid;
    float tx = tb[m], ty = tb[NG + m], tz = tb[2 * NG + m];
    float tn = fmaf(tx, tx, fmaf(ty, ty, tz * tz));
    float w = tn + (mask[b * NG + m] == 0.0f ? BIGF : 0.0f);
    t4[tid] = make_float4(-2.0f * tx, -2.0f * ty, -2.0f * tz, w);
  }
  __syncthreads();

  const int n0 = nch * 512 + tid;
  const int n1 = n0 + 256;
  const float* pb = preds + b * 5 * NP;
  const float px0 = pb[n0], py0 = pb[NP + n0], pz0 = pb[2 * NP + n0];
  const float px1 = pb[n1], py1 = pb[NP + n1], pz1 = pb[2 * NP + n1];

  // s = tn - 2*dot (+BIG if masked); pn^2 is thread-invariant so min/argmin
  // over s matches min/argmin over dist; clamp applied after the loop.
  float b00 = FLTMAX, b01 = FLTMAX, b10 = FLTMAX, b11 = FLTMAX;
  int i00 = 0, i01 = 0, i10 = 0, i11 = 0;
#pragma unroll 4
  for (int m = 0; m < 256; m += 2) {
    float4 t = t4[m];
    float4 u = t4[m + 1];
    float s00 = fmaf(px0, t.x, fmaf(py0, t.y, fmaf(pz0, t.z, t.w)));
    float s01 = fmaf(px0, u.x, fmaf(py0, u.y, fmaf(pz0, u.z, u.w)));
    float s10 = fmaf(px1, t.x, fmaf(py1, t.y, fmaf(pz1, t.z, t.w)));
    float s11 = fmaf(px1, u.x, fmaf(py1, u.y, fmaf(pz1, u.z, u.w)));
    if (s00 < b00) { b00 = s00; i00 = m; }
    if (s01 < b01) { b01 = s01; i01 = m + 1; }
    if (s10 < b10) { b10 = s10; i10 = m; }
    if (s11 < b11) { b11 = s11; i11 = m + 1; }
  }
  float bv0, bv1;
  int bi0, bi1;
  if (b01 < b00 || (b01 == b00 && i01 < i00)) { bv0 = b01; bi0 = i01; } else { bv0 = b00; bi0 = i00; }
  if (b11 < b10 || (b11 == b10 && i11 < i10)) { bv1 = b11; bi1 = i11; } else { bv1 = b10; bi1 = i10; }

  float pn0 = fmaf(px0, px0, fmaf(py0, py0, pz0 * pz0));
  float pn1 = fmaf(px1, px1, fmaf(py1, py1, pz1 * pz1));
  float d0 = fmaxf(bv0 + pn0, 0.0f);
  float d1 = fmaxf(bv1 + pn1, 0.0f);
  unsigned long long pk0 = ((unsigned long long)__float_as_uint(d0) << 32) | (unsigned)(mbase + bi0);
  unsigned long long pk1 = ((unsigned long long)__float_as_uint(d1) << 32) | (unsigned)(mbase + bi1);
  atomicMin(&pmin[b * NP + n0], pk0);
  atomicMin(&pmin[b * NP + n1], pk1);
}

// grid: 32 b * 4 mchunk * 8 npart = 1024 blocks. 512 targets/block (2 per
// thread), 256 preds staged in LDS. Min only -> u32 atomicMin on float bits.
__global__ __launch_bounds__(256) void k_tgt(const float* __restrict__ preds,
                                             const float* __restrict__ target,
                                             unsigned* __restrict__ tmin) {
  __shared__ float4 p4[256];
  const int bx = blockIdx.x;
  const int b = bx >> 5;
  const int mch = (bx >> 3) & 3;
  const int np_ = bx & 7;
  const int tid = threadIdx.x;
  const float* pb = preds + b * 5 * NP;
  {
    int n = np_ * 256 + tid;
    float px = pb[n], py = pb[NP + n], pz = pb[2 * NP + n];
    float pn2 = fmaf(px, px, fmaf(py, py, pz * pz));
    p4[tid] = make_float4(-2.0f * px, -2.0f * py, -2.0f * pz, pn2);
  }
  __syncthreads();

  const int m0 = mch * 512 + tid;
  const int m1 = m0 + 256;
  const float* tb = target + b * 4 * NG;
  const float tx0 = tb[m0], ty0 = tb[NG + m0], tz0 = tb[2 * NG + m0];
  const float tx1 = tb[m1], ty1 = tb[NG + m1], tz1 = tb[2 * NG + m1];

  float b00 = FLTMAX, b01 = FLTMAX, b10 = FLTMAX, b11 = FLTMAX;
#pragma unroll 4
  for (int n = 0; n < 256; n += 2) {
    float4 p = p4[n];
    float4 q = p4[n + 1];
    b00 = fminf(b00, fmaf(tx0, p.x, fmaf(ty0, p.y, fmaf(tz0, p.z, p.w))));
    b01 = fminf(b01, fmaf(tx0, q.x, fmaf(ty0, q.y, fmaf(tz0, q.z, q.w))));
    b10 = fminf(b10, fmaf(tx1, p.x, fmaf(ty1, p.y, fmaf(tz1, p.z, p.w))));
    b11 = fminf(b11, fmaf(tx1, q.x, fmaf(ty1, q.y, fmaf(tz1, q.z, q.w))));
  }
  float tn0 = fmaf(tx0, tx0, fmaf(ty0, ty0, tz0 * tz0));
  float tn1 = fmaf(tx1, tx1, fmaf(ty1, ty1, tz1 * tz1));
  float d0 = fmaxf(fminf(b00, b01) + tn0, 0.0f);
  float d1 = fmaxf(fminf(b10, b11) + tn1, 0.0f);
  atomicMin(&tmin[b * NG + m0], __float_as_uint(d0));
  atomicMin(&tmin[b * NG + m1], __float_as_uint(d1));
}

// combine pred partials: unpack min dist + argmin, gather matched target_E,
// plus entropy / hit-count / E*hit elementwise pieces.
__global__ __launch_bounds__(256) void k_pred_fin(const unsigned long long* __restrict__ pmin,
                                                  const float* __restrict__ preds,
                                                  const float* __restrict__ target,
                                                  float* __restrict__ acc) {
  const int i = blockIdx.x * 256 + threadIdx.x;  // 65536
  const int b = i >> 11;
  const int n = i & 2047;
  unsigned long long pk = pmin[i];
  float best = __uint_as_float((unsigned)(pk >> 32));
  int idx = (int)(pk & 0xffffffffu);
  float mE = target[b * 4 * NG + 3 * NG + idx];
  const float* pb = preds + b * 5 * NP;
  float pE = pb[3 * NP + n];
  float ph = pb[4 * NP + n];
  float localE = fabsf(pE - mE);
  float ent = ph * logf(ph + EPSF) + (1.0f - ph) * logf(1.0f - ph + EPSF);
  wave_acc(best, &acc[0]);
  wave_acc(localE, &acc[1]);
  wave_acc(ent, &acc[2]);
  wave_acc(ph, &acc[8 + b]);
  wave_acc(pE * ph, &acc[40 + b]);
}

__global__ __launch_bounds__(256) void k_tgt_fin(const unsigned* __restrict__ tmin,
                                                 const float* __restrict__ mask,
                                                 float* __restrict__ acc) {
  const int i = blockIdx.x * 256 + threadIdx.x;  // 65536
  const int b = i >> 11;
  float d = __uint_as_float(tmin[i]);
  float msk = mask[i];
  wave_acc(d * msk, &acc[3]);
  wave_acc(msk, &acc[4]);
  wave_acc(msk, &acc[72 + b]);
}

__global__ __launch_bounds__(256) void k_kld(const float* __restrict__ mu,
                                             const float* __restrict__ logvar,
                                             float* __restrict__ acc) {
  int i = blockIdx.x * 256 + threadIdx.x;  // B*L = 8192 exactly
  float m = mu[i], lv = logvar[i];
  float term = 1.0f + lv - m * m - expf(lv);
  wave_acc(term, &acc[5]);
}

__global__ __launch_bounds__(64) void k_final(const float* __restrict__ acc,
                                              const float* __restrict__ e_init,
                                              const float* __restrict__ kl_weight,
                                              float* __restrict__ out) {
  int t = threadIdx.x;
  float hitsq = 0.0f, esq = 0.0f;
  if (t < BB) {
    float dh = acc[8 + t] - acc[72 + t];
    hitsq = dh * dh;
    float de = acc[40 + t] - e_init[t];
    esq = de * de;
  }
  for (int o = 32; o > 0; o >>= 1) {
    hitsq += __shfl_down(hitsq, o);
    esq += __shfl_down(esq, o);
  }
  if (t == 0) {
    const float invBN = 1.0f / (float)(BB * NP);
    float chamfer_pred = acc[0] * invBN;
    float localE = acc[1] * invBN;
    float ent = -acc[2] * invBN;
    float chamfer_tgt = acc[3] / acc[4];
    float kld = -0.5f * acc[5] / (float)BB;
    float hit = hitsq / (float)BB;
    float ge = esq / (float)BB;

    float loss_chamf = (chamfer_tgt + chamfer_pred) * 0.001f;  // LAMBDA_CHAMFER
    float losskld = kl_weight[0] * kld;
    float loss_ge = 10.0f * ge;    // LAMBDA_E_SUM
    float loss_hit = 20.0f * hit;  // LAMBDA_HIT
    float loss_ent = 0.1f * ent;   // LAMBDA_HIT_ENTROPY

    float total = loss_chamf + localE + losskld + loss_ge + loss_hit + loss_ent;
    out[0] = total;
    out[1] = loss_chamf;
    out[2] = localE;
    out[3] = loss_ge;
    out[4] = loss_hit;
    out[5] = losskld;
  }
}

extern "C" void kernel_launch(void* const* d_in, const int* in_sizes, int n_in,
                              void* d_out, int out_size, void* d_ws, size_t ws_size,
                              hipStream_t stream) {
  const float* preds = (const float*)d_in[0];
  const float* target = (const float*)d_in[1];
  const float* mask = (const float*)d_in[2];
  const float* mu = (const float*)d_in[3];
  const float* logvar = (const float*)d_in[4];
  const float* e_init = (const float*)d_in[5];
  const float* kl_weight = (const float*)d_in[6];
  float* acc = (float*)d_ws;
  unsigned long long* pmin = (unsigned long long*)((char*)d_ws + PRED_OFF);
  unsigned* tmin = (unsigned*)((char*)d_ws + TGT_OFF);
  float* out = (float*)d_out;

  hipMemsetAsync(acc, 0, ACC_FLOATS * sizeof(float), stream);
  hipMemsetAsync((char*)d_ws + PRED_OFF, 0xFF,
                 (size_t)BB * NP * 8 + (size_t)BB * NG * 4, stream);

  k_pred<<<BB * 4 * 8, 256, 0, stream>>>(preds, target, mask, pmin);
  k_tgt<<<BB * 4 * 8, 256, 0, stream>>>(preds, target, tmin);
  k_pred_fin<<<BB * NP / 256, 256, 0, stream>>>(pmin, preds, target, acc);
  k_tgt_fin<<<BB * NG / 256, 256, 0, stream>>>(tmin, mask, acc);
  k_kld<<<(BB * LDIM) / 256, 256, 0, stream>>>(mu, logvar, acc);
  k_final<<<1, 64, 0, stream>>>(acc, e_init, kl_weight, out);
}

// Round 3
// 109.456 us; speedup vs baseline: 2.1107x; 1.6780x over previous
//
#include <hip/hip_runtime.h>

#define BB 32
#define NP 2048
#define NG 2048
#define LDIM 256
#define EPSF 1e-6f
#define BIGF 1e18f
#define FLTMAX 3.4e38f
#define MT 128  // m-tile staged in LDS per block

// ws layout:
//  [0, 416)           : float acc[104] (zeroed)
//  [4096, 4096+512K)  : u64 pred packed min (dist_bits<<32 | idx), init 0xFF
//  [4096+512K, +256K) : u32 tgt min dist bits, init 0xFF
#define ACC_FLOATS 104
#define PRED_OFF 4096
#define TGT_OFF (4096 + NP * BB * 8)

// acc indices: 0 sum_min_pred, 1 sum|dE|, 2 sum_entropy, 3 sum_min_tgt*mask,
// 4 mask_sum, 5 kld_sum, 8+b per-b hit sum, 40+b per-b E*hit, 72+b per-b mask.

// grid: 32 b * 2 nch * 16 mp = 1024 blocks. Each thread owns 4 n-points
// (1024 n per nch), 128 m staged in LDS. Partial min/argmin combined across
// mp via packed-u64 atomicMin (d>=0 -> bits monotonic; tie -> smallest idx,
// matching jnp.argmin first-index).
__global__ __launch_bounds__(256) void k_pred(const float* __restrict__ preds,
                                              const float* __restrict__ target,
                                              const float* __restrict__ mask,
                                              unsigned long long* __restrict__ pmin) {
  __shared__ float4 t4[MT];
  const int bx = blockIdx.x;
  const int b = bx >> 5;
  const int nch = (bx >> 4) & 1;
  const int mp = bx & 15;
  const int tid = threadIdx.x;
  const float* tb = target + b * 4 * NG;
  const int mbase = mp * MT;
  if (tid < MT) {
    int m = mbase + tid;
    float tx = tb[m], ty = tb[NG + m], tz = tb[2 * NG + m];
    float tn = fmaf(tx, tx, fmaf(ty, ty, tz * tz));
    float w = tn + (mask[b * NG + m] == 0.0f ? BIGF : 0.0f);
    t4[tid] = make_float4(-2.0f * tx, -2.0f * ty, -2.0f * tz, w);
  }
  __syncthreads();

  const int n0 = nch * 1024 + tid;
  const float* pb = preds + b * 5 * NP;
  const float px0 = pb[n0], py0 = pb[NP + n0], pz0 = pb[2 * NP + n0];
  const float px1 = pb[n0 + 256], py1 = pb[NP + n0 + 256], pz1 = pb[2 * NP + n0 + 256];
  const float px2 = pb[n0 + 512], py2 = pb[NP + n0 + 512], pz2 = pb[2 * NP + n0 + 512];
  const float px3 = pb[n0 + 768], py3 = pb[NP + n0 + 768], pz3 = pb[2 * NP + n0 + 768];

  // s = tn - 2*dot (+BIG if masked); pn^2 thread-invariant -> fold out of loop.
  float b0a = FLTMAX, b0b = FLTMAX, b1a = FLTMAX, b1b = FLTMAX;
  float b2a = FLTMAX, b2b = FLTMAX, b3a = FLTMAX, b3b = FLTMAX;
  int i0a = 0, i0b = 0, i1a = 0, i1b = 0, i2a = 0, i2b = 0, i3a = 0, i3b = 0;
#pragma unroll 4
  for (int m = 0; m < MT; m += 2) {
    float4 t = t4[m];
    float4 u = t4[m + 1];
    float s0a = fmaf(px0, t.x, fmaf(py0, t.y, fmaf(pz0, t.z, t.w)));
    float s1a = fmaf(px1, t.x, fmaf(py1, t.y, fmaf(pz1, t.z, t.w)));
    float s2a = fmaf(px2, t.x, fmaf(py2, t.y, fmaf(pz2, t.z, t.w)));
    float s3a = fmaf(px3, t.x, fmaf(py3, t.y, fmaf(pz3, t.z, t.w)));
    float s0b = fmaf(px0, u.x, fmaf(py0, u.y, fmaf(pz0, u.z, u.w)));
    float s1b = fmaf(px1, u.x, fmaf(py1, u.y, fmaf(pz1, u.z, u.w)));
    float s2b = fmaf(px2, u.x, fmaf(py2, u.y, fmaf(pz2, u.z, u.w)));
    float s3b = fmaf(px3, u.x, fmaf(py3, u.y, fmaf(pz3, u.z, u.w)));
    if (s0a < b0a) { b0a = s0a; i0a = m; }
    if (s1a < b1a) { b1a = s1a; i1a = m; }
    if (s2a < b2a) { b2a = s2a; i2a = m; }
    if (s3a < b3a) { b3a = s3a; i3a = m; }
    if (s0b < b0b) { b0b = s0b; i0b = m + 1; }
    if (s1b < b1b) { b1b = s1b; i1b = m + 1; }
    if (s2b < b2b) { b2b = s2b; i2b = m + 1; }
    if (s3b < b3b) { b3b = s3b; i3b = m + 1; }
  }

  float pn0 = fmaf(px0, px0, fmaf(py0, py0, pz0 * pz0));
  float pn1 = fmaf(px1, px1, fmaf(py1, py1, pz1 * pz1));
  float pn2 = fmaf(px2, px2, fmaf(py2, py2, pz2 * pz2));
  float pn3 = fmaf(px3, px3, fmaf(py3, py3, pz3 * pz3));
  float bv; int bi;
  unsigned long long* base = &pmin[b * NP];

  if (b0b < b0a || (b0b == b0a && i0b < i0a)) { bv = b0b; bi = i0b; } else { bv = b0a; bi = i0a; }
  atomicMin(&base[n0], ((unsigned long long)__float_as_uint(fmaxf(bv + pn0, 0.0f)) << 32) | (unsigned)(mbase + bi));
  if (b1b < b1a || (b1b == b1a && i1b < i1a)) { bv = b1b; bi = i1b; } else { bv = b1a; bi = i1a; }
  atomicMin(&base[n0 + 256], ((unsigned long long)__float_as_uint(fmaxf(bv + pn1, 0.0f)) << 32) | (unsigned)(mbase + bi));
  if (b2b < b2a || (b2b == b2a && i2b < i2a)) { bv = b2b; bi = i2b; } else { bv = b2a; bi = i2a; }
  atomicMin(&base[n0 + 512], ((unsigned long long)__float_as_uint(fmaxf(bv + pn2, 0.0f)) << 32) | (unsigned)(mbase + bi));
  if (b3b < b3a || (b3b == b3a && i3b < i3a)) { bv = b3b; bi = i3b; } else { bv = b3a; bi = i3a; }
  atomicMin(&base[n0 + 768], ((unsigned long long)__float_as_uint(fmaxf(bv + pn3, 0.0f)) << 32) | (unsigned)(mbase + bi));
}

// grid: 32 b * 2 mch * 16 np = 1024 blocks. 4 targets per thread, 128 preds
// in LDS. Min only -> u32 atomicMin on float bits.
__global__ __launch_bounds__(256) void k_tgt(const float* __restrict__ preds,
                                             const float* __restrict__ target,
                                             unsigned* __restrict__ tmin) {
  __shared__ float4 p4[MT];
  const int bx = blockIdx.x;
  const int b = bx >> 5;
  const int mch = (bx >> 4) & 1;
  const int np_ = bx & 15;
  const int tid = threadIdx.x;
  const float* pb = preds + b * 5 * NP;
  if (tid < MT) {
    int n = np_ * MT + tid;
    float px = pb[n], py = pb[NP + n], pz = pb[2 * NP + n];
    float pn2 = fmaf(px, px, fmaf(py, py, pz * pz));
    p4[tid] = make_float4(-2.0f * px, -2.0f * py, -2.0f * pz, pn2);
  }
  __syncthreads();

  const int m0 = mch * 1024 + tid;
  const float* tb = target + b * 4 * NG;
  const float tx0 = tb[m0], ty0 = tb[NG + m0], tz0 = tb[2 * NG + m0];
  const float tx1 = tb[m0 + 256], ty1 = tb[NG + m0 + 256], tz1 = tb[2 * NG + m0 + 256];
  const float tx2 = tb[m0 + 512], ty2 = tb[NG + m0 + 512], tz2 = tb[2 * NG + m0 + 512];
  const float tx3 = tb[m0 + 768], ty3 = tb[NG + m0 + 768], tz3 = tb[2 * NG + m0 + 768];

  float b0a = FLTMAX, b0b = FLTMAX, b1a = FLTMAX, b1b = FLTMAX;
  float b2a = FLTMAX, b2b = FLTMAX, b3a = FLTMAX, b3b = FLTMAX;
#pragma unroll 4
  for (int n = 0; n < MT; n += 2) {
    float4 p = p4[n];
    float4 q = p4[n + 1];
    b0a = fminf(b0a, fmaf(tx0, p.x, fmaf(ty0, p.y, fmaf(tz0, p.z, p.w))));
    b1a = fminf(b1a, fmaf(tx1, p.x, fmaf(ty1, p.y, fmaf(tz1, p.z, p.w))));
    b2a = fminf(b2a, fmaf(tx2, p.x, fmaf(ty2, p.y, fmaf(tz2, p.z, p.w))));
    b3a = fminf(b3a, fmaf(tx3, p.x, fmaf(ty3, p.y, fmaf(tz3, p.z, p.w))));
    b0b = fminf(b0b, fmaf(tx0, q.x, fmaf(ty0, q.y, fmaf(tz0, q.z, q.w))));
    b1b = fminf(b1b, fmaf(tx1, q.x, fmaf(ty1, q.y, fmaf(tz1, q.z, q.w))));
    b2b = fminf(b2b, fmaf(tx2, q.x, fmaf(ty2, q.y, fmaf(tz2, q.z, q.w))));
    b3b = fminf(b3b, fmaf(tx3, q.x, fmaf(ty3, q.y, fmaf(tz3, q.z, q.w))));
  }
  float tn0 = fmaf(tx0, tx0, fmaf(ty0, ty0, tz0 * tz0));
  float tn1 = fmaf(tx1, tx1, fmaf(ty1, ty1, tz1 * tz1));
  float tn2 = fmaf(tx2, tx2, fmaf(ty2, ty2, tz2 * tz2));
  float tn3 = fmaf(tx3, tx3, fmaf(ty3, ty3, tz3 * tz3));
  unsigned* base = &tmin[b * NG];
  atomicMin(&base[m0], __float_as_uint(fmaxf(fminf(b0a, b0b) + tn0, 0.0f)));
  atomicMin(&base[m0 + 256], __float_as_uint(fmaxf(fminf(b1a, b1b) + tn1, 0.0f)));
  atomicMin(&base[m0 + 512], __float_as_uint(fmaxf(fminf(b2a, b2b) + tn2, 0.0f)));
  atomicMin(&base[m0 + 768], __float_as_uint(fmaxf(fminf(b3a, b3b) + tn3, 0.0f)));
}

// Fused combine: blocks [0,128) pred side, [128,256) tgt side, [256,264) kld.
// Block-level LDS reduction -> <=5 atomics per block (kills the same-address
// atomic serialization that made the old fin kernels 46 us at 0.4% VALUBusy).
__global__ __launch_bounds__(256) void k_fin(const unsigned long long* __restrict__ pmin,
                                             const unsigned* __restrict__ tmin,
                                             const float* __restrict__ preds,
                                             const float* __restrict__ target,
                                             const float* __restrict__ mask,
                                             const float* __restrict__ mu,
                                             const float* __restrict__ logvar,
                                             float* __restrict__ acc) {
  __shared__ float red[4][8];
  const int bx = blockIdx.x;
  const int tid = threadIdx.x;
  const int wave = tid >> 6, lane = tid & 63;
  float q0 = 0.0f, q1 = 0.0f, q2 = 0.0f, q3 = 0.0f, q4 = 0.0f;
  int nq, a0, a1, a2, a3 = 0, a4 = 0;

  if (bx < 128) {
    const int b = bx >> 2;  // 4 blocks per b, 512 contiguous elems each
    const float* pb = preds + b * 5 * NP;
    const float* te = target + b * 4 * NG + 3 * NG;
#pragma unroll
    for (int e = 0; e < 2; e++) {
      int i = bx * 512 + e * 256 + tid;
      int n = i & 2047;
      unsigned long long pk = pmin[i];
      float best = __uint_as_float((unsigned)(pk >> 32));
      int idx = (int)(pk & 0xffffffffu);
      float mE = te[idx];
      float pE = pb[3 * NP + n];
      float ph = pb[4 * NP + n];
      q0 += best;
      q1 += fabsf(pE - mE);
      q2 += ph * logf(ph + EPSF) + (1.0f - ph) * logf(1.0f - ph + EPSF);
      q3 += ph;
      q4 += pE * ph;
    }
    nq = 5; a0 = 0; a1 = 1; a2 = 2; a3 = 8 + b; a4 = 40 + b;
  } else if (bx < 256) {
    const int bb = bx - 128;
    const int b = bb >> 2;
#pragma unroll
    for (int e = 0; e < 2; e++) {
      int i = bb * 512 + e * 256 + tid;
      float d = __uint_as_float(tmin[i]);
      float msk = mask[i];
      q0 += d * msk;
      q1 += msk;
      q2 += msk;
    }
    nq = 3; a0 = 3; a1 = 4; a2 = 72 + b;
  } else {
    const int bb = bx - 256;  // 8 blocks, 1024 elems each (B*L = 8192)
#pragma unroll
    for (int e = 0; e < 4; e++) {
      int i = bb * 1024 + e * 256 + tid;
      float m = mu[i], lv = logvar[i];
      q0 += 1.0f + lv - m * m - expf(lv);
    }
    nq = 1; a0 = 5; a1 = 0; a2 = 0;
  }

  float qs[5] = {q0, q1, q2, q3, q4};
  int ai[5] = {a0, a1, a2, a3, a4};
  for (int k = 0; k < nq; k++) {
    float v = qs[k];
    v += __shfl_down(v, 32);
    v += __shfl_down(v, 16);
    v += __shfl_down(v, 8);
    v += __shfl_down(v, 4);
    v += __shfl_down(v, 2);
    v += __shfl_down(v, 1);
    if (lane == 0) red[wave][k] = v;
  }
  __syncthreads();
  if (tid < nq) {
    float s = red[0][tid] + red[1][tid] + red[2][tid] + red[3][tid];
    atomicAdd(&acc[ai[tid]], s);
  }
}

__global__ __launch_bounds__(64) void k_final(const float* __restrict__ acc,
                                              const float* __restrict__ e_init,
                                              const float* __restrict__ kl_weight,
                                              float* __restrict__ out) {
  int t = threadIdx.x;
  float hitsq = 0.0f, esq = 0.0f;
  if (t < BB) {
    float dh = acc[8 + t] - acc[72 + t];
    hitsq = dh * dh;
    float de = acc[40 + t] - e_init[t];
    esq = de * de;
  }
  for (int o = 32; o > 0; o >>= 1) {
    hitsq += __shfl_down(hitsq, o);
    esq += __shfl_down(esq, o);
  }
  if (t == 0) {
    const float invBN = 1.0f / (float)(BB * NP);
    float chamfer_pred = acc[0] * invBN;
    float localE = acc[1] * invBN;
    float ent = -acc[2] * invBN;
    float chamfer_tgt = acc[3] / acc[4];
    float kld = -0.5f * acc[5] / (float)BB;
    float hit = hitsq / (float)BB;
    float ge = esq / (float)BB;

    float loss_chamf = (chamfer_tgt + chamfer_pred) * 0.001f;  // LAMBDA_CHAMFER
    float losskld = kl_weight[0] * kld;
    float loss_ge = 10.0f * ge;    // LAMBDA_E_SUM
    float loss_hit = 20.0f * hit;  // LAMBDA_HIT
    float loss_ent = 0.1f * ent;   // LAMBDA_HIT_ENTROPY

    float total = loss_chamf + localE + losskld + loss_ge + loss_hit + loss_ent;
    out[0] = total;
    out[1] = loss_chamf;
    out[2] = localE;
    out[3] = loss_ge;
    out[4] = loss_hit;
    out[5] = losskld;
  }
}

extern "C" void kernel_launch(void* const* d_in, const int* in_sizes, int n_in,
                              void* d_out, int out_size, void* d_ws, size_t ws_size,
                              hipStream_t stream) {
  const float* preds = (const float*)d_in[0];
  const float* target = (const float*)d_in[1];
  const float* mask = (const float*)d_in[2];
  const float* mu = (const float*)d_in[3];
  const float* logvar = (const float*)d_in[4];
  const float* e_init = (const float*)d_in[5];
  const float* kl_weight = (const float*)d_in[6];
  float* acc = (float*)d_ws;
  unsigned long long* pmin = (unsigned long long*)((char*)d_ws + PRED_OFF);
  unsigned* tmin = (unsigned*)((char*)d_ws + TGT_OFF);
  float* out = (float*)d_out;

  hipMemsetAsync(acc, 0, ACC_FLOATS * sizeof(float), stream);
  hipMemsetAsync((char*)d_ws + PRED_OFF, 0xFF,
                 (size_t)BB * NP * 8 + (size_t)BB * NG * 4, stream);

  k_pred<<<1024, 256, 0, stream>>>(preds, target, mask, pmin);
  k_tgt<<<1024, 256, 0, stream>>>(preds, target, tmin);
  k_fin<<<264, 256, 0, stream>>>(pmin, tmin, preds, target, mask, mu, logvar, acc);
  k_final<<<1, 64, 0, stream>>>(acc, e_init, kl_weight, out);
}

// Round 4
// 106.810 us; speedup vs baseline: 2.1630x; 1.0248x over previous
//
#include <hip/hip_runtime.h>

#define BB 32
#define NP 2048
#define NG 2048
#define EPSF 1e-6f
#define BIGF 1e18f
#define FLTMAX 3.4e38f
#define MT 128   // m-tile staged in LDS per block
#define MP 16    // partials per side

// ws layout (all regions fully overwritten every call -> no init memsets):
//  [0, 8448)            : fpart[264][8] floats (k_fin per-block partial sums)
//  [65536, +8MB)        : pred partials u64 [b][mp][n]  (dist_bits<<32 | idx)
//  [65536+8MB, +4MB)    : tgt partials f32 [b][np][m]
#define FPART_OFF 0
#define PPART_OFF 65536
#define TPART_OFF (65536 + BB * MP * NP * 8)

// Fused pairwise kernel. Blocks [0,2048): pred side (masked min+argmin over
// targets); blocks [2048,4096): tgt side (unmasked min over preds).
// Decomposition per side: 32 b * 4 chunk * 16 part. Each thread owns 2 points,
// 128 opposite-side points staged in LDS (broadcast reads, conflict-free).
// launch_bounds(256,8) caps VGPR at 64 -> 8 waves/SIMD (full occupancy).
__global__ __launch_bounds__(256, 8) void k_pair(const float* __restrict__ preds,
                                                 const float* __restrict__ target,
                                                 const float* __restrict__ mask,
                                                 unsigned long long* __restrict__ ppart,
                                                 float* __restrict__ tpart) {
  __shared__ float4 s4[MT];
  const int bx = blockIdx.x;
  const int tid = threadIdx.x;

  if (bx < 2048) {
    // ---- pred side ----
    const int b = bx >> 6;
    const int nch = (bx >> 4) & 3;
    const int mp = bx & 15;
    const float* tb = target + b * 4 * NG;
    const int mbase = mp * MT;
    if (tid < MT) {
      int m = mbase + tid;
      float tx = tb[m], ty = tb[NG + m], tz = tb[2 * NG + m];
      float tn = fmaf(tx, tx, fmaf(ty, ty, tz * tz));
      float w = tn + (mask[b * NG + m] == 0.0f ? BIGF : 0.0f);  // fold BIG mask
      s4[tid] = make_float4(-2.0f * tx, -2.0f * ty, -2.0f * tz, w);
    }
    __syncthreads();

    const int n0 = nch * 512 + tid;
    const float* pb = preds + b * 5 * NP;
    const float px0 = pb[n0], py0 = pb[NP + n0], pz0 = pb[2 * NP + n0];
    const float px1 = pb[n0 + 256], py1 = pb[NP + n0 + 256], pz1 = pb[2 * NP + n0 + 256];

    // s = tn - 2*dot (+BIG if masked); pn^2 thread-invariant -> folded out.
    float b0 = FLTMAX, b1 = FLTMAX;
    int i0 = 0, i1 = 0;
#pragma unroll 2
    for (int m = 0; m < MT; m++) {
      float4 t = s4[m];
      float s0 = fmaf(px0, t.x, fmaf(py0, t.y, fmaf(pz0, t.z, t.w)));
      float s1 = fmaf(px1, t.x, fmaf(py1, t.y, fmaf(pz1, t.z, t.w)));
      if (s0 < b0) { b0 = s0; i0 = m; }  // strict < keeps first index
      if (s1 < b1) { b1 = s1; i1 = m; }
    }
    float pn0 = fmaf(px0, px0, fmaf(py0, py0, pz0 * pz0));
    float pn1 = fmaf(px1, px1, fmaf(py1, py1, pz1 * pz1));
    float d0 = fmaxf(b0 + pn0, 0.0f);
    float d1 = fmaxf(b1 + pn1, 0.0f);
    unsigned long long* row = &ppart[(b * MP + mp) * NP];
    row[n0] = ((unsigned long long)__float_as_uint(d0) << 32) | (unsigned)(mbase + i0);
    row[n0 + 256] = ((unsigned long long)__float_as_uint(d1) << 32) | (unsigned)(mbase + i1);
  } else {
    // ---- tgt side ----
    const int bb = bx - 2048;
    const int b = bb >> 6;
    const int mch = (bb >> 4) & 3;
    const int np_ = bb & 15;
    const float* pb = preds + b * 5 * NP;
    if (tid < MT) {
      int n = np_ * MT + tid;
      float px = pb[n], py = pb[NP + n], pz = pb[2 * NP + n];
      float pn2 = fmaf(px, px, fmaf(py, py, pz * pz));
      s4[tid] = make_float4(-2.0f * px, -2.0f * py, -2.0f * pz, pn2);
    }
    __syncthreads();

    const int m0 = mch * 512 + tid;
    const float* tb = target + b * 4 * NG;
    const float tx0 = tb[m0], ty0 = tb[NG + m0], tz0 = tb[2 * NG + m0];
    const float tx1 = tb[m0 + 256], ty1 = tb[NG + m0 + 256], tz1 = tb[2 * NG + m0 + 256];

    float c0 = FLTMAX, c1 = FLTMAX;
#pragma unroll 2
    for (int n = 0; n < MT; n++) {
      float4 p = s4[n];
      c0 = fminf(c0, fmaf(tx0, p.x, fmaf(ty0, p.y, fmaf(tz0, p.z, p.w))));
      c1 = fminf(c1, fmaf(tx1, p.x, fmaf(ty1, p.y, fmaf(tz1, p.z, p.w))));
    }
    float tn0 = fmaf(tx0, tx0, fmaf(ty0, ty0, tz0 * tz0));
    float tn1 = fmaf(tx1, tx1, fmaf(ty1, ty1, tz1 * tz1));
    float* row = &tpart[(b * MP + np_) * NG];
    row[m0] = fmaxf(c0 + tn0, 0.0f);
    row[m0 + 256] = fmaxf(c1 + tn1, 0.0f);
  }
}

// Combine: blocks [0,128) pred side, [128,256) tgt side, [256,264) kld.
// Reduces 16 partials per point, computes elementwise pieces, block-level
// LDS reduction, writes 5 partial sums to a private slot (no atomics).
__global__ __launch_bounds__(256) void k_fin(const unsigned long long* __restrict__ ppart,
                                             const float* __restrict__ tpart,
                                             const float* __restrict__ preds,
                                             const float* __restrict__ target,
                                             const float* __restrict__ mask,
                                             const float* __restrict__ mu,
                                             const float* __restrict__ logvar,
                                             float* __restrict__ fpart) {
  __shared__ float red[4][8];
  const int bx = blockIdx.x;
  const int tid = threadIdx.x;
  const int wave = tid >> 6, lane = tid & 63;
  float q0 = 0.0f, q1 = 0.0f, q2 = 0.0f, q3 = 0.0f, q4 = 0.0f;

  if (bx < 128) {
    const int b = bx >> 2;
    const float* pb = preds + b * 5 * NP;
    const float* te = target + b * 4 * NG + 3 * NG;
#pragma unroll
    for (int e = 0; e < 2; e++) {
      int i = bx * 512 + e * 256 + tid;
      int n = i & 2047;
      unsigned long long best = 0xFFFFFFFFFFFFFFFFull;
      const unsigned long long* col = &ppart[b * MP * NP + n];
#pragma unroll
      for (int mp = 0; mp < MP; mp++) {
        unsigned long long v = col[mp * NP];  // coalesced across lanes
        best = v < best ? v : best;           // min packed: dist then index
      }
      float bd = __uint_as_float((unsigned)(best >> 32));
      int idx = (int)(best & 0xffffffffu);
      float mE = te[idx];
      float pE = pb[3 * NP + n];
      float ph = pb[4 * NP + n];
      q0 += bd;
      q1 += fabsf(pE - mE);
      q2 += ph * logf(ph + EPSF) + (1.0f - ph) * logf(1.0f - ph + EPSF);
      q3 += ph;
      q4 += pE * ph;
    }
  } else if (bx < 256) {
    const int bb = bx - 128;
    const int b = bb >> 2;
#pragma unroll
    for (int e = 0; e < 2; e++) {
      int i = bb * 512 + e * 256 + tid;
      int m = i & 2047;
      float d = FLTMAX;
      const float* col = &tpart[b * MP * NG + m];
#pragma unroll
      for (int np_ = 0; np_ < MP; np_++) d = fminf(d, col[np_ * NG]);
      float msk = mask[i];
      q0 += d * msk;  // sum min_dist_tgt * mask
      q1 += msk;      // global mask sum
      q2 += msk;      // per-b mask sum (same value, separate slot)
    }
  } else {
    const int bb = bx - 256;  // B*L = 8192 over 8 blocks
#pragma unroll
    for (int e = 0; e < 4; e++) {
      int i = bb * 1024 + e * 256 + tid;
      float m = mu[i], lv = logvar[i];
      q0 += 1.0f + lv - m * m - expf(lv);
    }
  }

  float qs[5] = {q0, q1, q2, q3, q4};
  for (int k = 0; k < 5; k++) {
    float v = qs[k];
    v += __shfl_down(v, 32);
    v += __shfl_down(v, 16);
    v += __shfl_down(v, 8);
    v += __shfl_down(v, 4);
    v += __shfl_down(v, 2);
    v += __shfl_down(v, 1);
    if (lane == 0) red[wave][k] = v;
  }
  __syncthreads();
  if (tid < 5) fpart[bx * 8 + tid] = red[0][tid] + red[1][tid] + red[2][tid] + red[3][tid];
}

// Single-block final reduction over fpart rows + loss assembly.
__global__ __launch_bounds__(256) void k_final(const float* __restrict__ fpart,
                                               const float* __restrict__ e_init,
                                               const float* __restrict__ kl_weight,
                                               float* __restrict__ out) {
  __shared__ float red[4][8];
  const int t = threadIdx.x;
  const int wave = t >> 6, lane = t & 63;
  float g[8] = {0, 0, 0, 0, 0, 0, 0, 0};
  // g0 sum_min_pred, g1 sum|dE|, g2 entropy, g3 sum d*msk, g4 mask_sum,
  // g5 kld_sum, g6 hit_sq_sum, g7 esq_sum
  if (t < 128) {
    const float* r = &fpart[t * 8];
    g[0] = r[0]; g[1] = r[1]; g[2] = r[2];
    const float* r2 = &fpart[(128 + t) * 8];
    g[3] = r2[0]; g[4] = r2[1];
  }
  if (t < 8) g[5] = fpart[(256 + t) * 8];
  if (t < BB) {
    float hit = 0.0f, eh = 0.0f, mk = 0.0f;
#pragma unroll
    for (int k = 0; k < 4; k++) {
      hit += fpart[(4 * t + k) * 8 + 3];
      eh += fpart[(4 * t + k) * 8 + 4];
      mk += fpart[(128 + 4 * t + k) * 8 + 2];
    }
    float dh = hit - mk;
    g[6] = dh * dh;
    float de = eh - e_init[t];
    g[7] = de * de;
  }
  for (int k = 0; k < 8; k++) {
    float v = g[k];
    v += __shfl_down(v, 32);
    v += __shfl_down(v, 16);
    v += __shfl_down(v, 8);
    v += __shfl_down(v, 4);
    v += __shfl_down(v, 2);
    v += __shfl_down(v, 1);
    if (lane == 0) red[wave][k] = v;
  }
  __syncthreads();
  if (t == 0) {
    float s[8];
    for (int k = 0; k < 8; k++) s[k] = red[0][k] + red[1][k] + red[2][k] + red[3][k];
    const float invBN = 1.0f / (float)(BB * NP);
    float chamfer_pred = s[0] * invBN;
    float localE = s[1] * invBN;
    float ent = -s[2] * invBN;
    float chamfer_tgt = s[3] / s[4];
    float kld = -0.5f * s[5] / (float)BB;
    float hit = s[6] / (float)BB;
    float ge = s[7] / (float)BB;

    float loss_chamf = (chamfer_tgt + chamfer_pred) * 0.001f;  // LAMBDA_CHAMFER
    float losskld = kl_weight[0] * kld;
    float loss_ge = 10.0f * ge;    // LAMBDA_E_SUM
    float loss_hit = 20.0f * hit;  // LAMBDA_HIT
    float loss_ent = 0.1f * ent;   // LAMBDA_HIT_ENTROPY

    float total = loss_chamf + localE + losskld + loss_ge + loss_hit + loss_ent;
    out[0] = total;
    out[1] = loss_chamf;
    out[2] = localE;
    out[3] = loss_ge;
    out[4] = loss_hit;
    out[5] = losskld;
  }
}

extern "C" void kernel_launch(void* const* d_in, const int* in_sizes, int n_in,
                              void* d_out, int out_size, void* d_ws, size_t ws_size,
                              hipStream_t stream) {
  const float* preds = (const float*)d_in[0];
  const float* target = (const float*)d_in[1];
  const float* mask = (const float*)d_in[2];
  const float* mu = (const float*)d_in[3];
  const float* logvar = (const float*)d_in[4];
  const float* e_init = (const float*)d_in[5];
  const float* kl_weight = (const float*)d_in[6];
  float* fpart = (float*)((char*)d_ws + FPART_OFF);
  unsigned long long* ppart = (unsigned long long*)((char*)d_ws + PPART_OFF);
  float* tpart = (float*)((char*)d_ws + TPART_OFF);
  float* out = (float*)d_out;

  k_pair<<<4096, 256, 0, stream>>>(preds, target, mask, ppart, tpart);
  k_fin<<<264, 256, 0, stream>>>(ppart, tpart, preds, target, mask, mu, logvar, fpart);
  k_final<<<1, 256, 0, stream>>>(fpart, e_init, kl_weight, out);
}

// Round 5
// 105.294 us; speedup vs baseline: 2.1942x; 1.0144x over previous
//
#include <hip/hip_runtime.h>

#define BB 32
#define NP 2048
#define NG 2048
#define EPSF 1e-6f
#define BIGF 1e18f
#define FLTMAX 3.4e38f
#define MT 128   // m-tile staged in LDS per block
#define MP 16    // partials per side
#define TPT 8    // points per thread (amortizes ds_read_b128 over 8 pts)

// ws layout (all regions fully overwritten every call -> no init memsets):
//  [0, 8448)            : fpart[264][8] floats (k_fin per-block partial sums)
//  [65536, +8MB)        : pred partials u64 [b][mp][n]  (dist_bits<<32 | idx)
//  [65536+8MB, +4MB)    : tgt partials f32 [b][np][m]
#define FPART_OFF 0
#define PPART_OFF 65536
#define TPART_OFF (65536 + BB * MP * NP * 8)

// Fused pairwise kernel. Blocks [0,512): pred side (masked min+argmin over
// targets); blocks [512,1024): tgt side (unmasked min over preds).
// Per side: 32 b * 16 mp. Each thread owns 8 points (stride 256), 128
// opposite-side points staged in LDS. One ds_read_b128 feeds 8 points ->
// LDS pipe ~10us total, VALU ~17-20us is the limit. 1024 blocks = 4/CU.
__global__ __launch_bounds__(256, 4) void k_pair(const float* __restrict__ preds,
                                                 const float* __restrict__ target,
                                                 const float* __restrict__ mask,
                                                 unsigned long long* __restrict__ ppart,
                                                 float* __restrict__ tpart) {
  __shared__ float4 s4[MT];
  const int bx = blockIdx.x;
  const int tid = threadIdx.x;

  if (bx < 512) {
    // ---- pred side ----
    const int b = bx >> 4;
    const int mp = bx & 15;
    const float* tb = target + b * 4 * NG;
    const int mbase = mp * MT;
    if (tid < MT) {
      int m = mbase + tid;
      float tx = tb[m], ty = tb[NG + m], tz = tb[2 * NG + m];
      float tn = fmaf(tx, tx, fmaf(ty, ty, tz * tz));
      float w = tn + (mask[b * NG + m] == 0.0f ? BIGF : 0.0f);  // fold BIG mask
      s4[tid] = make_float4(-2.0f * tx, -2.0f * ty, -2.0f * tz, w);
    }
    __syncthreads();

    const float* pb = preds + b * 5 * NP;
    float px[TPT], py[TPT], pz[TPT], bv[TPT];
    int bi[TPT];
#pragma unroll
    for (int k = 0; k < TPT; k++) {
      int n = tid + k * 256;
      px[k] = pb[n];
      py[k] = pb[NP + n];
      pz[k] = pb[2 * NP + n];
      bv[k] = FLTMAX;
      bi[k] = 0;
    }

    // s = tn - 2*dot (+BIG if masked); pn^2 thread-invariant -> folded out.
#pragma unroll 2
    for (int m = 0; m < MT; m++) {
      float4 t = s4[m];
#pragma unroll
      for (int k = 0; k < TPT; k++) {
        float s = fmaf(px[k], t.x, fmaf(py[k], t.y, fmaf(pz[k], t.z, t.w)));
        if (s < bv[k]) { bv[k] = s; bi[k] = m; }  // strict < keeps first index
      }
    }

    unsigned long long* row = &ppart[(b * MP + mp) * NP];
#pragma unroll
    for (int k = 0; k < TPT; k++) {
      float pn = fmaf(px[k], px[k], fmaf(py[k], py[k], pz[k] * pz[k]));
      float d = fmaxf(bv[k] + pn, 0.0f);
      row[tid + k * 256] =
          ((unsigned long long)__float_as_uint(d) << 32) | (unsigned)(mbase + bi[k]);
    }
  } else {
    // ---- tgt side ----
    const int bb = bx - 512;
    const int b = bb >> 4;
    const int np_ = bb & 15;
    const float* pb = preds + b * 5 * NP;
    if (tid < MT) {
      int n = np_ * MT + tid;
      float px = pb[n], py = pb[NP + n], pz = pb[2 * NP + n];
      float pn2 = fmaf(px, px, fmaf(py, py, pz * pz));
      s4[tid] = make_float4(-2.0f * px, -2.0f * py, -2.0f * pz, pn2);
    }
    __syncthreads();

    const float* tb = target + b * 4 * NG;
    float tx[TPT], ty[TPT], tz[TPT], cv[TPT];
#pragma unroll
    for (int k = 0; k < TPT; k++) {
      int m = tid + k * 256;
      tx[k] = tb[m];
      ty[k] = tb[NG + m];
      tz[k] = tb[2 * NG + m];
      cv[k] = FLTMAX;
    }

#pragma unroll 2
    for (int n = 0; n < MT; n++) {
      float4 p = s4[n];
#pragma unroll
      for (int k = 0; k < TPT; k++)
        cv[k] = fminf(cv[k], fmaf(tx[k], p.x, fmaf(ty[k], p.y, fmaf(tz[k], p.z, p.w))));
    }

    float* row = &tpart[(b * MP + np_) * NG];
#pragma unroll
    for (int k = 0; k < TPT; k++) {
      float tn = fmaf(tx[k], tx[k], fmaf(ty[k], ty[k], tz[k] * tz[k]));
      row[tid + k * 256] = fmaxf(cv[k] + tn, 0.0f);
    }
  }
}

// Combine: blocks [0,128) pred side, [128,256) tgt side, [256,264) kld.
// Reduces 16 partials per point, computes elementwise pieces, block-level
// LDS reduction, writes 5 partial sums to a private slot (no atomics).
__global__ __launch_bounds__(256) void k_fin(const unsigned long long* __restrict__ ppart,
                                             const float* __restrict__ tpart,
                                             const float* __restrict__ preds,
                                             const float* __restrict__ target,
                                             const float* __restrict__ mask,
                                             const float* __restrict__ mu,
                                             const float* __restrict__ logvar,
                                             float* __restrict__ fpart) {
  __shared__ float red[4][8];
  const int bx = blockIdx.x;
  const int tid = threadIdx.x;
  const int wave = tid >> 6, lane = tid & 63;
  float q0 = 0.0f, q1 = 0.0f, q2 = 0.0f, q3 = 0.0f, q4 = 0.0f;

  if (bx < 128) {
    const int b = bx >> 2;
    const float* pb = preds + b * 5 * NP;
    const float* te = target + b * 4 * NG + 3 * NG;
#pragma unroll
    for (int e = 0; e < 2; e++) {
      int i = bx * 512 + e * 256 + tid;
      int n = i & 2047;
      unsigned long long best = 0xFFFFFFFFFFFFFFFFull;
      const unsigned long long* col = &ppart[b * MP * NP + n];
#pragma unroll
      for (int mp = 0; mp < MP; mp++) {
        unsigned long long v = col[mp * NP];  // coalesced across lanes
        best = v < best ? v : best;           // min packed: dist then index
      }
      float bd = __uint_as_float((unsigned)(best >> 32));
      int idx = (int)(best & 0xffffffffu);
      float mE = te[idx];
      float pE = pb[3 * NP + n];
      float ph = pb[4 * NP + n];
      q0 += bd;
      q1 += fabsf(pE - mE);
      q2 += ph * logf(ph + EPSF) + (1.0f - ph) * logf(1.0f - ph + EPSF);
      q3 += ph;
      q4 += pE * ph;
    }
  } else if (bx < 256) {
    const int bb = bx - 128;
    const int b = bb >> 2;
#pragma unroll
    for (int e = 0; e < 2; e++) {
      int i = bb * 512 + e * 256 + tid;
      int m = i & 2047;
      float d = FLTMAX;
      const float* col = &tpart[b * MP * NG + m];
#pragma unroll
      for (int np_ = 0; np_ < MP; np_++) d = fminf(d, col[np_ * NG]);
      float msk = mask[i];
      q0 += d * msk;  // sum min_dist_tgt * mask
      q1 += msk;      // global mask sum
      q2 += msk;      // per-b mask sum (same value, separate slot)
    }
  } else {
    const int bb = bx - 256;  // B*L = 8192 over 8 blocks
#pragma unroll
    for (int e = 0; e < 4; e++) {
      int i = bb * 1024 + e * 256 + tid;
      float m = mu[i], lv = logvar[i];
      q0 += 1.0f + lv - m * m - expf(lv);
    }
  }

  float qs[5] = {q0, q1, q2, q3, q4};
  for (int k = 0; k < 5; k++) {
    float v = qs[k];
    v += __shfl_down(v, 32);
    v += __shfl_down(v, 16);
    v += __shfl_down(v, 8);
    v += __shfl_down(v, 4);
    v += __shfl_down(v, 2);
    v += __shfl_down(v, 1);
    if (lane == 0) red[wave][k] = v;
  }
  __syncthreads();
  if (tid < 5) fpart[bx * 8 + tid] = red[0][tid] + red[1][tid] + red[2][tid] + red[3][tid];
}

// Single-block final reduction over fpart rows + loss assembly.
__global__ __launch_bounds__(256) void k_final(const float* __restrict__ fpart,
                                               const float* __restrict__ e_init,
                                               const float* __restrict__ kl_weight,
                                               float* __restrict__ out) {
  __shared__ float red[4][8];
  const int t = threadIdx.x;
  const int wave = t >> 6, lane = t & 63;
  float g[8] = {0, 0, 0, 0, 0, 0, 0, 0};
  // g0 sum_min_pred, g1 sum|dE|, g2 entropy, g3 sum d*msk, g4 mask_sum,
  // g5 kld_sum, g6 hit_sq_sum, g7 esq_sum
  if (t < 128) {
    const float* r = &fpart[t * 8];
    g[0] = r[0]; g[1] = r[1]; g[2] = r[2];
    const float* r2 = &fpart[(128 + t) * 8];
    g[3] = r2[0]; g[4] = r2[1];
  }
  if (t < 8) g[5] = fpart[(256 + t) * 8];
  if (t < BB) {
    float hit = 0.0f, eh = 0.0f, mk = 0.0f;
#pragma unroll
    for (int k = 0; k < 4; k++) {
      hit += fpart[(4 * t + k) * 8 + 3];
      eh += fpart[(4 * t + k) * 8 + 4];
      mk += fpart[(128 + 4 * t + k) * 8 + 2];
    }
    float dh = hit - mk;
    g[6] = dh * dh;
    float de = eh - e_init[t];
    g[7] = de * de;
  }
  for (int k = 0; k < 8; k++) {
    float v = g[k];
    v += __shfl_down(v, 32);
    v += __shfl_down(v, 16);
    v += __shfl_down(v, 8);
    v += __shfl_down(v, 4);
    v += __shfl_down(v, 2);
    v += __shfl_down(v, 1);
    if (lane == 0) red[wave][k] = v;
  }
  __syncthreads();
  if (t == 0) {
    float s[8];
    for (int k = 0; k < 8; k++) s[k] = red[0][k] + red[1][k] + red[2][k] + red[3][k];
    const float invBN = 1.0f / (float)(BB * NP);
    float chamfer_pred = s[0] * invBN;
    float localE = s[1] * invBN;
    float ent = -s[2] * invBN;
    float chamfer_tgt = s[3] / s[4];
    float kld = -0.5f * s[5] / (float)BB;
    float hit = s[6] / (float)BB;
    float ge = s[7] / (float)BB;

    float loss_chamf = (chamfer_tgt + chamfer_pred) * 0.001f;  // LAMBDA_CHAMFER
    float losskld = kl_weight[0] * kld;
    float loss_ge = 10.0f * ge;    // LAMBDA_E_SUM
    float loss_hit = 20.0f * hit;  // LAMBDA_HIT
    float loss_ent = 0.1f * ent;   // LAMBDA_HIT_ENTROPY

    float total = loss_chamf + localE + losskld + loss_ge + loss_hit + loss_ent;
    out[0] = total;
    out[1] = loss_chamf;
    out[2] = localE;
    out[3] = loss_ge;
    out[4] = loss_hit;
    out[5] = losskld;
  }
}

extern "C" void kernel_launch(void* const* d_in, const int* in_sizes, int n_in,
                              void* d_out, int out_size, void* d_ws, size_t ws_size,
                              hipStream_t stream) {
  const float* preds = (const float*)d_in[0];
  const float* target = (const float*)d_in[1];
  const float* mask = (const float*)d_in[2];
  const float* mu = (const float*)d_in[3];
  const float* logvar = (const float*)d_in[4];
  const float* e_init = (const float*)d_in[5];
  const float* kl_weight = (const float*)d_in[6];
  float* fpart = (float*)((char*)d_ws + FPART_OFF);
  unsigned long long* ppart = (unsigned long long*)((char*)d_ws + PPART_OFF);
  float* tpart = (float*)((char*)d_ws + TPART_OFF);
  float* out = (float*)d_out;

  k_pair<<<1024, 256, 0, stream>>>(preds, target, mask, ppart, tpart);
  k_fin<<<264, 256, 0, stream>>>(ppart, tpart, preds, target, mask, mu, logvar, fpart);
  k_final<<<1, 256, 0, stream>>>(fpart, e_init, kl_weight, out);
}

// Round 6
// 103.892 us; speedup vs baseline: 2.2238x; 1.0135x over previous
//
#include <hip/hip_runtime.h>

#define BB 32
#define NP 2048
#define NG 2048
#define EPSF 1e-6f
#define BIGF 1e18f
#define FLTMAX 3.4e38f
#define MT 128   // m-tile staged in LDS per block
#define MP 16    // partials per side
#define TPT 4    // points per thread: ~40 live VGPRs -> fits 64-VGPR/8-wave occupancy

// ws layout (all regions fully overwritten every call -> no init memsets):
//  [0, 8448)            : fpart[264][8] floats (k_fin per-block partial sums)
//  [65536, +8MB)        : pred partials u64 [b][mp][n]  (dist_bits<<32 | idx)
//  [65536+8MB, +4MB)    : tgt partials f32 [b][np][m]
#define FPART_OFF 0
#define PPART_OFF 65536
#define TPART_OFF (65536 + BB * MP * NP * 8)

// Fused pairwise kernel. Blocks [0,1024): pred side (masked min+argmin over
// targets); blocks [1024,2048): tgt side (unmasked min over preds).
// Per side: 32 b * 2 nch * 16 mp. Each thread owns 4 points (stride 256),
// 128 opposite-side points staged in LDS (broadcast b128 reads).
// launch_bounds(256,8) caps VGPR at 64 -> 8 waves/SIMD, 32 waves/CU with
// 8 blocks/CU: latency-hiding was the R5 bottleneck (4 waves/SIMD).
__global__ __launch_bounds__(256, 8) void k_pair(const float* __restrict__ preds,
                                                 const float* __restrict__ target,
                                                 const float* __restrict__ mask,
                                                 unsigned long long* __restrict__ ppart,
                                                 float* __restrict__ tpart) {
  __shared__ float4 s4[MT];
  const int bx = blockIdx.x;
  const int tid = threadIdx.x;

  if (bx < 1024) {
    // ---- pred side ----
    const int b = bx >> 5;
    const int nch = (bx >> 4) & 1;
    const int mp = bx & 15;
    const float* tb = target + b * 4 * NG;
    const int mbase = mp * MT;
    if (tid < MT) {
      int m = mbase + tid;
      float tx = tb[m], ty = tb[NG + m], tz = tb[2 * NG + m];
      float tn = fmaf(tx, tx, fmaf(ty, ty, tz * tz));
      float w = tn + (mask[b * NG + m] == 0.0f ? BIGF : 0.0f);  // fold BIG mask
      s4[tid] = make_float4(-2.0f * tx, -2.0f * ty, -2.0f * tz, w);
    }
    __syncthreads();

    const float* pb = preds + b * 5 * NP;
    const int nbase = nch * 1024 + tid;
    float px[TPT], py[TPT], pz[TPT], bv[TPT];
    int bi[TPT];
#pragma unroll
    for (int k = 0; k < TPT; k++) {
      int n = nbase + k * 256;
      px[k] = pb[n];
      py[k] = pb[NP + n];
      pz[k] = pb[2 * NP + n];
      bv[k] = FLTMAX;
      bi[k] = 0;
    }

    // s = tn - 2*dot (+BIG if masked); pn^2 thread-invariant -> folded out.
#pragma unroll 4
    for (int m = 0; m < MT; m++) {
      float4 t = s4[m];
#pragma unroll
      for (int k = 0; k < TPT; k++) {
        float s = fmaf(px[k], t.x, fmaf(py[k], t.y, fmaf(pz[k], t.z, t.w)));
        if (s < bv[k]) { bv[k] = s; bi[k] = m; }  // strict < keeps first index
      }
    }

    unsigned long long* row = &ppart[(b * MP + mp) * NP];
#pragma unroll
    for (int k = 0; k < TPT; k++) {
      float pn = fmaf(px[k], px[k], fmaf(py[k], py[k], pz[k] * pz[k]));
      float d = fmaxf(bv[k] + pn, 0.0f);
      row[nbase + k * 256] =
          ((unsigned long long)__float_as_uint(d) << 32) | (unsigned)(mbase + bi[k]);
    }
  } else {
    // ---- tgt side ----
    const int bb = bx - 1024;
    const int b = bb >> 5;
    const int mch = (bb >> 4) & 1;
    const int np_ = bb & 15;
    const float* pb = preds + b * 5 * NP;
    if (tid < MT) {
      int n = np_ * MT + tid;
      float px = pb[n], py = pb[NP + n], pz = pb[2 * NP + n];
      float pn2 = fmaf(px, px, fmaf(py, py, pz * pz));
      s4[tid] = make_float4(-2.0f * px, -2.0f * py, -2.0f * pz, pn2);
    }
    __syncthreads();

    const float* tb = target + b * 4 * NG;
    const int mbase2 = mch * 1024 + tid;
    float tx[TPT], ty[TPT], tz[TPT], cv[TPT];
#pragma unroll
    for (int k = 0; k < TPT; k++) {
      int m = mbase2 + k * 256;
      tx[k] = tb[m];
      ty[k] = tb[NG + m];
      tz[k] = tb[2 * NG + m];
      cv[k] = FLTMAX;
    }

#pragma unroll 4
    for (int n = 0; n < MT; n++) {
      float4 p = s4[n];
#pragma unroll
      for (int k = 0; k < TPT; k++)
        cv[k] = fminf(cv[k], fmaf(tx[k], p.x, fmaf(ty[k], p.y, fmaf(tz[k], p.z, p.w))));
    }

    float* row = &tpart[(b * MP + np_) * NG];
#pragma unroll
    for (int k = 0; k < TPT; k++) {
      float tn = fmaf(tx[k], tx[k], fmaf(ty[k], ty[k], tz[k] * tz[k]));
      row[mbase2 + k * 256] = fmaxf(cv[k] + tn, 0.0f);
    }
  }
}

// Combine: blocks [0,128) pred side, [128,256) tgt side, [256,264) kld.
// Reduces 16 partials per point, computes elementwise pieces, block-level
// LDS reduction, writes 5 partial sums to a private slot (no atomics).
__global__ __launch_bounds__(256) void k_fin(const unsigned long long* __restrict__ ppart,
                                             const float* __restrict__ tpart,
                                             const float* __restrict__ preds,
                                             const float* __restrict__ target,
                                             const float* __restrict__ mask,
                                             const float* __restrict__ mu,
                                             const float* __restrict__ logvar,
                                             float* __restrict__ fpart) {
  __shared__ float red[4][8];
  const int bx = blockIdx.x;
  const int tid = threadIdx.x;
  const int wave = tid >> 6, lane = tid & 63;
  float q0 = 0.0f, q1 = 0.0f, q2 = 0.0f, q3 = 0.0f, q4 = 0.0f;

  if (bx < 128) {
    const int b = bx >> 2;
    const float* pb = preds + b * 5 * NP;
    const float* te = target + b * 4 * NG + 3 * NG;
#pragma unroll
    for (int e = 0; e < 2; e++) {
      int i = bx * 512 + e * 256 + tid;
      int n = i & 2047;
      unsigned long long best = 0xFFFFFFFFFFFFFFFFull;
      const unsigned long long* col = &ppart[b * MP * NP + n];
#pragma unroll
      for (int mp = 0; mp < MP; mp++) {
        unsigned long long v = col[mp * NP];  // coalesced across lanes
        best = v < best ? v : best;           // min packed: dist then index
      }
      float bd = __uint_as_float((unsigned)(best >> 32));
      int idx = (int)(best & 0xffffffffu);
      float mE = te[idx];
      float pE = pb[3 * NP + n];
      float ph = pb[4 * NP + n];
      q0 += bd;
      q1 += fabsf(pE - mE);
      q2 += ph * logf(ph + EPSF) + (1.0f - ph) * logf(1.0f - ph + EPSF);
      q3 += ph;
      q4 += pE * ph;
    }
  } else if (bx < 256) {
    const int bb = bx - 128;
    const int b = bb >> 2;
#pragma unroll
    for (int e = 0; e < 2; e++) {
      int i = bb * 512 + e * 256 + tid;
      int m = i & 2047;
      float d = FLTMAX;
      const float* col = &tpart[b * MP * NG + m];
#pragma unroll
      for (int np_ = 0; np_ < MP; np_++) d = fminf(d, col[np_ * NG]);
      float msk = mask[i];
      q0 += d * msk;  // sum min_dist_tgt * mask
      q1 += msk;      // global mask sum
      q2 += msk;      // per-b mask sum (same value, separate slot)
    }
  } else {
    const int bb = bx - 256;  // B*L = 8192 over 8 blocks
#pragma unroll
    for (int e = 0; e < 4; e++) {
      int i = bb * 1024 + e * 256 + tid;
      float m = mu[i], lv = logvar[i];
      q0 += 1.0f + lv - m * m - expf(lv);
    }
  }

  float qs[5] = {q0, q1, q2, q3, q4};
  for (int k = 0; k < 5; k++) {
    float v = qs[k];
    v += __shfl_down(v, 32);
    v += __shfl_down(v, 16);
    v += __shfl_down(v, 8);
    v += __shfl_down(v, 4);
    v += __shfl_down(v, 2);
    v += __shfl_down(v, 1);
    if (lane == 0) red[wave][k] = v;
  }
  __syncthreads();
  if (tid < 5) fpart[bx * 8 + tid] = red[0][tid] + red[1][tid] + red[2][tid] + red[3][tid];
}

// Single-block final reduction over fpart rows + loss assembly.
__global__ __launch_bounds__(256) void k_final(const float* __restrict__ fpart,
                                               const float* __restrict__ e_init,
                                               const float* __restrict__ kl_weight,
                                               float* __restrict__ out) {
  __shared__ float red[4][8];
  const int t = threadIdx.x;
  const int wave = t >> 6, lane = t & 63;
  float g[8] = {0, 0, 0, 0, 0, 0, 0, 0};
  // g0 sum_min_pred, g1 sum|dE|, g2 entropy, g3 sum d*msk, g4 mask_sum,
  // g5 kld_sum, g6 hit_sq_sum, g7 esq_sum
  if (t < 128) {
    const float* r = &fpart[t * 8];
    g[0] = r[0]; g[1] = r[1]; g[2] = r[2];
    const float* r2 = &fpart[(128 + t) * 8];
    g[3] = r2[0]; g[4] = r2[1];
  }
  if (t < 8) g[5] = fpart[(256 + t) * 8];
  if (t < BB) {
    float hit = 0.0f, eh = 0.0f, mk = 0.0f;
#pragma unroll
    for (int k = 0; k < 4; k++) {
      hit += fpart[(4 * t + k) * 8 + 3];
      eh += fpart[(4 * t + k) * 8 + 4];
      mk += fpart[(128 + 4 * t + k) * 8 + 2];
    }
    float dh = hit - mk;
    g[6] = dh * dh;
    float de = eh - e_init[t];
    g[7] = de * de;
  }
  for (int k = 0; k < 8; k++) {
    float v = g[k];
    v += __shfl_down(v, 32);
    v += __shfl_down(v, 16);
    v += __shfl_down(v, 8);
    v += __shfl_down(v, 4);
    v += __shfl_down(v, 2);
    v += __shfl_down(v, 1);
    if (lane == 0) red[wave][k] = v;
  }
  __syncthreads();
  if (t == 0) {
    float s[8];
    for (int k = 0; k < 8; k++) s[k] = red[0][k] + red[1][k] + red[2][k] + red[3][k];
    const float invBN = 1.0f / (float)(BB * NP);
    float chamfer_pred = s[0] * invBN;
    float localE = s[1] * invBN;
    float ent = -s[2] * invBN;
    float chamfer_tgt = s[3] / s[4];
    float kld = -0.5f * s[5] / (float)BB;
    float hit = s[6] / (float)BB;
    float ge = s[7] / (float)BB;

    float loss_chamf = (chamfer_tgt + chamfer_pred) * 0.001f;  // LAMBDA_CHAMFER
    float losskld = kl_weight[0] * kld;
    float loss_ge = 10.0f * ge;    // LAMBDA_E_SUM
    float loss_hit = 20.0f * hit;  // LAMBDA_HIT
    float loss_ent = 0.1f * ent;   // LAMBDA_HIT_ENTROPY

    float total = loss_chamf + localE + losskld + loss_ge + loss_hit + loss_ent;
    out[0] = total;
    out[1] = loss_chamf;
    out[2] = localE;
    out[3] = loss_ge;
    out[4] = loss_hit;
    out[5] = losskld;
  }
}

extern "C" void kernel_launch(void* const* d_in, const int* in_sizes, int n_in,
                              void* d_out, int out_size, void* d_ws, size_t ws_size,
                              hipStream_t stream) {
  const float* preds = (const float*)d_in[0];
  const float* target = (const float*)d_in[1];
  const float* mask = (const float*)d_in[2];
  const float* mu = (const float*)d_in[3];
  const float* logvar = (const float*)d_in[4];
  const float* e_init = (const float*)d_in[5];
  const float* kl_weight = (const float*)d_in[6];
  float* fpart = (float*)((char*)d_ws + FPART_OFF);
  unsigned long long* ppart = (unsigned long long*)((char*)d_ws + PPART_OFF);
  float* tpart = (float*)((char*)d_ws + TPART_OFF);
  float* out = (float*)d_out;

  k_pair<<<2048, 256, 0, stream>>>(preds, target, mask, ppart, tpart);
  k_fin<<<264, 256, 0, stream>>>(ppart, tpart, preds, target, mask, mu, logvar, fpart);
  k_final<<<1, 256, 0, stream>>>(fpart, e_init, kl_weight, out);
}